// Round 6
// baseline (600.925 us; speedup 1.0000x reference)
//
#include <hip/hip_runtime.h>
#include <math.h>

typedef unsigned short u16;
typedef __attribute__((ext_vector_type(8))) short s16x8;
typedef __attribute__((ext_vector_type(4))) float f32x4;

#define NB 8
#define NT 256
#define NL 24
#define NC 512
#define NH 8
#define ND 64
#define NR (NB*NT*NL)        // 49152 rows
#define NBT (NB*NT)          // 2048

__device__ __forceinline__ u16 f2bf(float f) {
    unsigned u = __float_as_uint(f);
    u = (u + 0x7fffu + ((u >> 16) & 1u)) >> 16;
    return (u16)u;
}
__device__ __forceinline__ float bf2f(u16 h) {
    return __uint_as_float(((unsigned)h) << 16);
}

// ---------------------------------------------------------------------------
// Kernel 1: convert inputs to bf16, transpose weights to [N][K] bf16,
//           precompute tanh(v_init).
// ---------------------------------------------------------------------------
__global__ void convert_kernel(const float* __restrict__ q, const float* __restrict__ kv,
                               const float* __restrict__ Wq, const float* __restrict__ Wkv,
                               const float* __restrict__ Wg, const float* __restrict__ Wm,
                               const float* __restrict__ v_init,
                               u16* __restrict__ qbf, u16* __restrict__ kvbf,
                               u16* __restrict__ Wq_t, u16* __restrict__ Wkv_t,
                               u16* __restrict__ Wg_t, u16* __restrict__ Wm_t,
                               float* __restrict__ tvi)
{
    const int stride = gridDim.x * blockDim.x;
    const int t0 = blockIdx.x * blockDim.x + threadIdx.x;

    const long long n4 = (long long)NR * NC / 4;
    for (long long i = t0; i < n4; i += stride) {
        float4 a = ((const float4*)q)[i];
        ushort4 oa;
        oa.x = f2bf(a.x); oa.y = f2bf(a.y); oa.z = f2bf(a.z); oa.w = f2bf(a.w);
        ((ushort4*)qbf)[i] = oa;
        float4 b = ((const float4*)kv)[i];
        ushort4 ob;
        ob.x = f2bf(b.x); ob.y = f2bf(b.y); ob.z = f2bf(b.z); ob.w = f2bf(b.w);
        ((ushort4*)kvbf)[i] = ob;
    }
    for (int e = t0; e < 512 * 512; e += stride) {
        int n = e >> 9, k = e & 511;
        Wq_t[e] = f2bf(Wq[k * 512 + n]);
        Wg_t[e] = f2bf(Wg[k * 512 + n]);
        Wm_t[e] = f2bf(Wm[k * 512 + n]);
    }
    for (int e = t0; e < 1024 * 512; e += stride) {
        int n = e >> 9, k = e & 511;
        Wkv_t[e] = f2bf(Wkv[k * 1024 + n]);
    }
    for (int e = t0; e < NL * NC; e += stride) {
        tvi[e] = tanhf(v_init[e]);
    }
}

// ---------------------------------------------------------------------------
// GEMM: C[M,N] = A[M,K=512] * Bt[N,K=512]^T (+bias, + mode-specific epilogue)
// 128x128 tile, BK=32, 4 waves. TRIPLE-buffered LDS, counted vmcnt (T4):
//   prologue: STAGE(tile0), STAGE(tile1)
//   iter t:   vmcnt(4) [tile t landed]; s_barrier; ds_read+MFMA buf[t%3];
//             STAGE(tile t+2 -> buf[(t+2)%3])
// buf (t+2)%3 was last read at iter t-1; iter-t barrier orders that read
// before this overwrite -> 1 barrier/iter, loads span 2 iters (never drain).
// ---------------------------------------------------------------------------
template <int MODE>
__global__ __launch_bounds__(256)
void gemm_kernel(const u16* __restrict__ A, int lda,
                 const u16* __restrict__ Bt,
                 const float* __restrict__ bias,
                 void* __restrict__ out, int ldo,
                 const float* __restrict__ extra)
{
    __shared__ __align__(16) u16 Alds[3][128 * 32];
    __shared__ __align__(16) u16 Blds[3][128 * 32];

    const int tid = threadIdx.x;
    const int mb = blockIdx.x, nb = blockIdx.y;
    const int wave = tid >> 6, lane = tid & 63;
    const int wr = wave >> 1, wc = wave & 1;
    const int lrow = lane & 15;
    const int lko = (lane >> 4) * 8;

    f32x4 acc[4][4] = {};

    // per-thread staging addresses (chunk ch = c*256+tid -> row=ch>>2, k8=(ch&3)*8)
    const int row_a[2] = { tid >> 2, (256 + tid) >> 2 };
    const int k8_a = (tid & 3) * 8;

#define STAGE(buf, k0)                                                          \
    do {                                                                        \
        _Pragma("unroll")                                                       \
        for (int c = 0; c < 2; ++c) {                                           \
            const u16* srcA = A + (size_t)(mb * 128 + row_a[c]) * lda + (k0) + k8_a; \
            u16* dstA = &Alds[buf][(c * 256 + wave * 64) * 8];                  \
            __builtin_amdgcn_global_load_lds(                                   \
                (const __attribute__((address_space(1))) void*)srcA,            \
                (__attribute__((address_space(3))) void*)dstA, 16, 0, 0);       \
        }                                                                       \
        _Pragma("unroll")                                                       \
        for (int c = 0; c < 2; ++c) {                                           \
            const u16* srcB = Bt + (size_t)(nb * 128 + row_a[c]) * 512 + (k0) + k8_a; \
            u16* dstB = &Blds[buf][(c * 256 + wave * 64) * 8];                  \
            __builtin_amdgcn_global_load_lds(                                   \
                (const __attribute__((address_space(1))) void*)srcB,            \
                (__attribute__((address_space(3))) void*)dstB, 16, 0, 0);       \
        }                                                                       \
    } while (0)

    STAGE(0, 0);
    STAGE(1, 32);

#pragma unroll
    for (int t = 0; t < 16; ++t) {
        // tile t's 4 loads complete (tile t+1's may remain in flight)
        if (t < 15) asm volatile("s_waitcnt vmcnt(4)" ::: "memory");
        else        asm volatile("s_waitcnt vmcnt(0)" ::: "memory");
        __builtin_amdgcn_s_barrier();   // all waves' tile-t loads landed

        const int cb = t % 3;           // literal after unroll
        s16x8 af[4], bfr[4];
#pragma unroll
        for (int m = 0; m < 4; ++m)
            af[m] = *(const s16x8*)&Alds[cb][(wr * 64 + m * 16 + lrow) * 32 + lko];
#pragma unroll
        for (int n = 0; n < 4; ++n)
            bfr[n] = *(const s16x8*)&Blds[cb][(wc * 64 + n * 16 + lrow) * 32 + lko];
#pragma unroll
        for (int m = 0; m < 4; ++m)
#pragma unroll
            for (int n = 0; n < 4; ++n)
                acc[m][n] = __builtin_amdgcn_mfma_f32_16x16x32_bf16(
                    af[m], bfr[n], acc[m][n], 0, 0, 0);

        if (t < 14) STAGE((t + 2) % 3, (t + 2) * 32);
    }
#undef STAGE

    // epilogue: C/D layout col=lane&15, row=(lane>>4)*4+j
    const int rbase = mb * 128 + wr * 64;
    const int cbase = nb * 128 + wc * 64;
#pragma unroll
    for (int m = 0; m < 4; ++m) {
#pragma unroll
        for (int n = 0; n < 4; ++n) {
            int row0 = rbase + m * 16 + ((lane >> 4) * 4);
            int col = cbase + n * 16 + (lane & 15);
            float bv = bias[col];
#pragma unroll
            for (int j = 0; j < 4; ++j) {
                int row = row0 + j;
                float v = acc[m][n][j] + bv;
                if constexpr (MODE == 0 || MODE == 1) {
                    ((u16*)out)[(size_t)row * ldo + col] = f2bf(v);
                } else if constexpr (MODE == 2) {
                    float g = 1.f / (1.f + __expf(-v));
                    float tv = extra[(row % NL) * NC + col];
                    ((u16*)out)[(size_t)row * ldo + col] = f2bf(fmaxf(g * tv, 0.f));
                } else {
                    float sc = extra[(size_t)row * NC + col];
                    ((float*)out)[(size_t)row * ldo + col] = v + sc;
                }
            }
        }
    }
}

// ---------------------------------------------------------------------------
// MFMA attention: block = 4 waves, one (b,t) per block, each wave does 2 heads.
// ---------------------------------------------------------------------------
__global__ __launch_bounds__(256)
void attn_kernel(const u16* __restrict__ qp, const u16* __restrict__ kvp,
                 const u16* __restrict__ vun, u16* __restrict__ xout)
{
    __shared__ __align__(16) u16 Plds[4][32 * 32];   // [row<32][k<32] per wave
    __shared__ __align__(16) u16 VTlds[4][64 * 32];  // [c<64][k<32]  per wave

    const int tid = threadIdx.x;
    const int wave = tid >> 6, lane = tid & 63;
    const int lr = lane & 15, lg = lane >> 4;
    const size_t rowbase = (size_t)blockIdx.x * NL;
    u16* P  = Plds[wave];
    u16* VT = VTlds[wave];

    for (int hh = 0; hh < 2; ++hh) {
        const int h = wave * 2 + hh;

        // ---- load fragments (rows clamped to 23: avoids OOB + inf in pad rows)
        s16x8 qf[2][2], kf[2][2], vf[2][2];
#pragma unroll
        for (int m = 0; m < 2; ++m) {
            int rq = m * 16 + lr; int r = rq > 23 ? 23 : rq;
            const u16* q_ = qp  + (rowbase + r) * 512  + h * 64 + lg * 8;
            const u16* k_ = kvp + (rowbase + r) * 1024 + h * 64 + lg * 8;
            const u16* v_ = vun + (rowbase + r) * 512  + h * 64 + lg * 8;
#pragma unroll
            for (int ks = 0; ks < 2; ++ks) {
                qf[m][ks] = *(const s16x8*)(q_ + ks * 32);
                kf[m][ks] = *(const s16x8*)(k_ + ks * 32);
                vf[m][ks] = *(const s16x8*)(v_ + ks * 32);
            }
        }

        // ---- row norms via in-register shfl_xor reduce
        float invq[2], invk[2], invv[2];
#pragma unroll
        for (int m = 0; m < 2; ++m) {
            float sq = 0.f, sk = 0.f, sv = 0.f;
#pragma unroll
            for (int ks = 0; ks < 2; ++ks)
#pragma unroll
                for (int j = 0; j < 8; ++j) {
                    float a = bf2f((u16)qf[m][ks][j]); sq += a * a;
                    float b = bf2f((u16)kf[m][ks][j]); sk += b * b;
                    float c = bf2f((u16)vf[m][ks][j]); sv += c * c;
                }
            sq += __shfl_xor(sq, 16); sq += __shfl_xor(sq, 32);
            sk += __shfl_xor(sk, 16); sk += __shfl_xor(sk, 32);
            sv += __shfl_xor(sv, 16); sv += __shfl_xor(sv, 32);
            invq[m] = 1.f / fmaxf(sqrtf(sq), 1e-12f);
            invk[m] = 1.f / fmaxf(sqrtf(sk), 1e-12f);
            invv[m] = 1.f / fmaxf(sqrtf(sv), 1e-12f);
        }

        // ---- S = Q K^T
        f32x4 sc[2][2] = {};
#pragma unroll
        for (int m = 0; m < 2; ++m)
#pragma unroll
            for (int n = 0; n < 2; ++n)
#pragma unroll
                for (int ks = 0; ks < 2; ++ks)
                    sc[m][n] = __builtin_amdgcn_mfma_f32_16x16x32_bf16(
                        qf[m][ks], kf[n][ks], sc[m][n], 0, 0, 0);

        // ---- scale + softmax (row r = m*16 + lg*4 + j, cols = lr / 16+lr)
#pragma unroll
        for (int m = 0; m < 2; ++m) {
#pragma unroll
            for (int j = 0; j < 4; ++j) {
                float nq = __shfl(invq[m], lg * 4 + j);
                float a0 = sc[m][0][j] * nq * invk[0] * 0.125f;
                float a1 = (lr < 8) ? sc[m][1][j] * nq * invk[1] * 0.125f : -3.0e38f;
                float mx = fmaxf(a0, a1);
#pragma unroll
                for (int d = 1; d < 16; d <<= 1) mx = fmaxf(mx, __shfl_xor(mx, d));
                float e0 = __expf(a0 - mx);
                float e1 = (lr < 8) ? __expf(a1 - mx) : 0.f;
                float s = e0 + e1;
#pragma unroll
                for (int d = 1; d < 16; d <<= 1) s += __shfl_xor(s, d);
                float inv = 1.f / s;
                int r = m * 16 + lg * 4 + j;
                P[r * 32 + lr]      = f2bf(e0 * inv);
                P[r * 32 + 16 + lr] = f2bf(e1 * inv);   // cols 24-31 get 0
            }
        }

        // ---- normalized V^T into LDS: V[r][c] -> VT[c*32 + r]
#pragma unroll
        for (int m = 0; m < 2; ++m)
#pragma unroll
            for (int ks = 0; ks < 2; ++ks)
#pragma unroll
                for (int j = 0; j < 8; ++j) {
                    int c = ks * 32 + lg * 8 + j;
                    int r = m * 16 + lr;
                    VT[c * 32 + r] = f2bf(bf2f((u16)vf[m][ks][j]) * invv[m]);
                }

        asm volatile("s_waitcnt lgkmcnt(0)" ::: "memory");
        __builtin_amdgcn_sched_barrier(0);

        // ---- X = P V
        s16x8 pa[2], vb[4];
#pragma unroll
        for (int m = 0; m < 2; ++m)
            pa[m] = *(const s16x8*)&P[(m * 16 + lr) * 32 + lg * 8];
#pragma unroll
        for (int n = 0; n < 4; ++n)
            vb[n] = *(const s16x8*)&VT[(n * 16 + lr) * 32 + lg * 8];

        f32x4 xa[2][4] = {};
#pragma unroll
        for (int m = 0; m < 2; ++m)
#pragma unroll
            for (int n = 0; n < 4; ++n)
                xa[m][n] = __builtin_amdgcn_mfma_f32_16x16x32_bf16(
                    pa[m], vb[n], xa[m][n], 0, 0, 0);

        // ---- store rows < 24
#pragma unroll
        for (int m = 0; m < 2; ++m)
#pragma unroll
            for (int n = 0; n < 4; ++n)
#pragma unroll
                for (int j = 0; j < 4; ++j) {
                    int r = m * 16 + lg * 4 + j;
                    if (r < 24)
                        xout[(rowbase + r) * 512 + h * 64 + n * 16 + lr] =
                            f2bf(xa[m][n][j]);
                }

        // wave-local LDS reuse across heads: in-order DS pipe + compiler waits
        asm volatile("s_waitcnt lgkmcnt(0)" ::: "memory");
        __builtin_amdgcn_sched_barrier(0);
    }
}

// ---------------------------------------------------------------------------
extern "C" void kernel_launch(void* const* d_in, const int* in_sizes, int n_in,
                              void* d_out, int out_size, void* d_ws, size_t ws_size,
                              hipStream_t stream)
{
    const float* q      = (const float*)d_in[0];
    const float* kv     = (const float*)d_in[1];
    const float* Wq     = (const float*)d_in[2];
    const float* bq     = (const float*)d_in[3];
    const float* Wkv    = (const float*)d_in[4];
    const float* bkv    = (const float*)d_in[5];
    const float* Wg     = (const float*)d_in[6];
    const float* bg     = (const float*)d_in[7];
    const float* v_init = (const float*)d_in[8];
    const float* Wm     = (const float*)d_in[9];
    const float* bm     = (const float*)d_in[10];

    char* ws = (char*)d_ws;
    const size_t SZ = (size_t)NR * NC;
    u16* buf0   = (u16*)(ws);                      // qbf -> later x
    u16* buf1   = (u16*)(ws + 2 * SZ);             // kvbf -> later v_unnorm
    u16* qp     = (u16*)(ws + 4 * SZ);
    u16* kvp    = (u16*)(ws + 6 * SZ);             // [R,1024]
    char* wbase = ws + 10 * SZ;
    u16* Wq_t   = (u16*)(wbase);
    u16* Wkv_t  = (u16*)(wbase + 512 * 512 * 2);
    u16* Wg_t   = (u16*)(wbase + 512 * 512 * 2 + 1024 * 512 * 2);
    u16* Wm_t   = (u16*)(wbase + 2 * 512 * 512 * 2 + 1024 * 512 * 2);
    float* tvi  = (float*)(wbase + 3 * 512 * 512 * 2 + 1024 * 512 * 2);

    convert_kernel<<<1024, 256, 0, stream>>>(q, kv, Wq, Wkv, Wg, Wm, v_init,
                                             buf0, buf1, Wq_t, Wkv_t, Wg_t, Wm_t, tvi);

    gemm_kernel<1><<<dim3(NR / 128, 8), 256, 0, stream>>>(buf1, 512, Wkv_t, bkv,
                                                          kvp, 1024, nullptr);
    gemm_kernel<0><<<dim3(NR / 128, 4), 256, 0, stream>>>(buf0, 512, Wq_t, bq,
                                                          qp, 512, nullptr);
    gemm_kernel<2><<<dim3(NR / 128, 4), 256, 0, stream>>>(kvp + 512, 1024, Wg_t, bg,
                                                          buf1, 512, tvi);

    attn_kernel<<<dim3(NBT), 256, 0, stream>>>(qp, kvp, buf1, buf0);

    gemm_kernel<3><<<dim3(NR / 128, 4), 256, 0, stream>>>(buf0, 512, Wm_t, bm,
                                                          d_out, 512, q);
}

// Round 7
// 580.661 us; speedup vs baseline: 1.0349x; 1.0349x over previous
//
#include <hip/hip_runtime.h>
#include <math.h>

typedef unsigned short u16;
typedef __attribute__((ext_vector_type(8))) short s16x8;
typedef __attribute__((ext_vector_type(4))) float f32x4;

#define NB 8
#define NT 256
#define NL 24
#define NC 512
#define NH 8
#define ND 64
#define NR (NB*NT*NL)        // 49152 rows
#define NBT (NB*NT)          // 2048

__device__ __forceinline__ u16 f2bf(float f) {
    unsigned u = __float_as_uint(f);
    u = (u + 0x7fffu + ((u >> 16) & 1u)) >> 16;
    return (u16)u;
}
__device__ __forceinline__ float bf2f(u16 h) {
    return __uint_as_float(((unsigned)h) << 16);
}

// ---------------------------------------------------------------------------
// Kernel 1: convert inputs to bf16, transpose weights to [N][K] bf16,
//           precompute tanh(v_init).
// ---------------------------------------------------------------------------
__global__ void convert_kernel(const float* __restrict__ q, const float* __restrict__ kv,
                               const float* __restrict__ Wq, const float* __restrict__ Wkv,
                               const float* __restrict__ Wg, const float* __restrict__ Wm,
                               const float* __restrict__ v_init,
                               u16* __restrict__ qbf, u16* __restrict__ kvbf,
                               u16* __restrict__ Wq_t, u16* __restrict__ Wkv_t,
                               u16* __restrict__ Wg_t, u16* __restrict__ Wm_t,
                               float* __restrict__ tvi)
{
    const int stride = gridDim.x * blockDim.x;
    const int t0 = blockIdx.x * blockDim.x + threadIdx.x;

    const long long n4 = (long long)NR * NC / 4;
    for (long long i = t0; i < n4; i += stride) {
        float4 a = ((const float4*)q)[i];
        ushort4 oa;
        oa.x = f2bf(a.x); oa.y = f2bf(a.y); oa.z = f2bf(a.z); oa.w = f2bf(a.w);
        ((ushort4*)qbf)[i] = oa;
        float4 b = ((const float4*)kv)[i];
        ushort4 ob;
        ob.x = f2bf(b.x); ob.y = f2bf(b.y); ob.z = f2bf(b.z); ob.w = f2bf(b.w);
        ((ushort4*)kvbf)[i] = ob;
    }
    for (int e = t0; e < 512 * 512; e += stride) {
        int n = e >> 9, k = e & 511;
        Wq_t[e] = f2bf(Wq[k * 512 + n]);
        Wg_t[e] = f2bf(Wg[k * 512 + n]);
        Wm_t[e] = f2bf(Wm[k * 512 + n]);
    }
    for (int e = t0; e < 1024 * 512; e += stride) {
        int n = e >> 9, k = e & 511;
        Wkv_t[e] = f2bf(Wkv[k * 1024 + n]);
    }
    for (int e = t0; e < NL * NC; e += stride) {
        tvi[e] = tanhf(v_init[e]);
    }
}

// ---------------------------------------------------------------------------
// GEMM: C[M,N] = A[M,K=512] * Bt[N,K=512]^T (+bias, + mode-specific epilogue)
// 128x128 tile, BK=32, 4 waves, triple-buffered LDS, counted vmcnt.
//
// LDS swizzle (both-sides, rule #21): tile = [128 rows][4 chunks of 16B].
//   LDS[row][c] holds GLOBAL chunk (c ^ ((row>>1)&3)).
//   - stage: linear LDS dest (wave-uniform base + lane*16B); per-thread global
//     source k8s = ((tid&3) ^ ((tid>>3)&3))*8   (same for both half-tiles).
//   - read: chunk index = lg ^ ((lrow>>1)&3)  -> banks spread to perfect
//     2-way (free, m136) instead of 8-way on the 64B row stride.
//
// MFMA operands SWAPPED (acc = Bfrag x Afrag): lane holds C[row=m*16+lr]
// [cols n*16 + lg*4 .. +3] -> vectorized epilogue (ushort4 / float4).
// ---------------------------------------------------------------------------
template <int MODE>
__global__ __launch_bounds__(256)
void gemm_kernel(const u16* __restrict__ A, int lda,
                 const u16* __restrict__ Bt,
                 const float* __restrict__ bias,
                 void* __restrict__ out, int ldo,
                 const float* __restrict__ extra)
{
    __shared__ __align__(16) u16 Alds[3][128 * 32];
    __shared__ __align__(16) u16 Blds[3][128 * 32];

    const int tid = threadIdx.x;
    const int mb = blockIdx.x, nb = blockIdx.y;
    const int wave = tid >> 6, lane = tid & 63;
    const int wr = wave >> 1, wc = wave & 1;
    const int lrow = lane & 15;
    const int lg = lane >> 4;
    // swizzled k-chunk for LDS reads (per-lane constant)
    const int rko = (lg ^ ((lrow >> 1) & 3)) * 8;

    f32x4 acc[4][4] = {};

    // staging: dst chunk ch = c*256+tid -> row=ch>>2, chunk=ch&3
    const int row_a[2] = { tid >> 2, (256 + tid) >> 2 };
    const int k8s = (((tid & 3) ^ ((tid >> 3) & 3)) * 8);   // swizzled source

#define STAGE(buf, k0)                                                          \
    do {                                                                        \
        _Pragma("unroll")                                                       \
        for (int c = 0; c < 2; ++c) {                                           \
            const u16* srcA = A + (size_t)(mb * 128 + row_a[c]) * lda + (k0) + k8s; \
            u16* dstA = &Alds[buf][(c * 256 + wave * 64) * 8];                  \
            __builtin_amdgcn_global_load_lds(                                   \
                (const __attribute__((address_space(1))) void*)srcA,            \
                (__attribute__((address_space(3))) void*)dstA, 16, 0, 0);       \
        }                                                                       \
        _Pragma("unroll")                                                       \
        for (int c = 0; c < 2; ++c) {                                           \
            const u16* srcB = Bt + (size_t)(nb * 128 + row_a[c]) * 512 + (k0) + k8s; \
            u16* dstB = &Blds[buf][(c * 256 + wave * 64) * 8];                  \
            __builtin_amdgcn_global_load_lds(                                   \
                (const __attribute__((address_space(1))) void*)srcB,            \
                (__attribute__((address_space(3))) void*)dstB, 16, 0, 0);       \
        }                                                                       \
    } while (0)

    STAGE(0, 0);
    STAGE(1, 32);

#pragma unroll
    for (int t = 0; t < 16; ++t) {
        if (t < 15) asm volatile("s_waitcnt vmcnt(4)" ::: "memory");
        else        asm volatile("s_waitcnt vmcnt(0)" ::: "memory");
        __builtin_amdgcn_s_barrier();   // all waves' tile-t loads landed

        const int cb = t % 3;           // literal after unroll
        s16x8 af[4], bfr[4];
#pragma unroll
        for (int m = 0; m < 4; ++m)
            af[m] = *(const s16x8*)&Alds[cb][(wr * 64 + m * 16 + lrow) * 32 + rko];
#pragma unroll
        for (int n = 0; n < 4; ++n)
            bfr[n] = *(const s16x8*)&Blds[cb][(wc * 64 + n * 16 + lrow) * 32 + rko];
        // swapped operands: lane holds 4 consecutive C-COLUMNS at one row
#pragma unroll
        for (int m = 0; m < 4; ++m)
#pragma unroll
            for (int n = 0; n < 4; ++n)
                acc[m][n] = __builtin_amdgcn_mfma_f32_16x16x32_bf16(
                    bfr[n], af[m], acc[m][n], 0, 0, 0);

        if (t < 14) STAGE((t + 2) % 3, (t + 2) * 32);
    }
#undef STAGE

    // epilogue (transposed acc): row = m*16 + lr, cols = n*16 + lg*4 + j
    const int rbase = mb * 128 + wr * 64;
    const int cbase = nb * 128 + wc * 64;
#pragma unroll
    for (int m = 0; m < 4; ++m) {
        const int row = rbase + m * 16 + lrow;
#pragma unroll
        for (int n = 0; n < 4; ++n) {
            const int col0 = cbase + n * 16 + lg * 4;
            float4 bv = *(const float4*)&bias[col0];
            float v0 = acc[m][n][0] + bv.x;
            float v1 = acc[m][n][1] + bv.y;
            float v2 = acc[m][n][2] + bv.z;
            float v3 = acc[m][n][3] + bv.w;
            if constexpr (MODE == 0 || MODE == 1) {
                ushort4 o = { f2bf(v0), f2bf(v1), f2bf(v2), f2bf(v3) };
                *(ushort4*)&((u16*)out)[(size_t)row * ldo + col0] = o;
            } else if constexpr (MODE == 2) {
                float4 tv = *(const float4*)&extra[(row % NL) * NC + col0];
                float g0 = 1.f / (1.f + __expf(-v0));
                float g1 = 1.f / (1.f + __expf(-v1));
                float g2 = 1.f / (1.f + __expf(-v2));
                float g3 = 1.f / (1.f + __expf(-v3));
                ushort4 o = { f2bf(fmaxf(g0 * tv.x, 0.f)), f2bf(fmaxf(g1 * tv.y, 0.f)),
                              f2bf(fmaxf(g2 * tv.z, 0.f)), f2bf(fmaxf(g3 * tv.w, 0.f)) };
                *(ushort4*)&((u16*)out)[(size_t)row * ldo + col0] = o;
            } else {
                float4 sc = *(const float4*)&extra[(size_t)row * NC + col0];
                float4 o = { v0 + sc.x, v1 + sc.y, v2 + sc.z, v3 + sc.w };
                *(float4*)&((float*)out)[(size_t)row * ldo + col0] = o;
            }
        }
    }
}

// ---------------------------------------------------------------------------
// MFMA attention: block = 4 waves, one (b,t) per block, each wave does 2 heads.
// ---------------------------------------------------------------------------
__global__ __launch_bounds__(256)
void attn_kernel(const u16* __restrict__ qp, const u16* __restrict__ kvp,
                 const u16* __restrict__ vun, u16* __restrict__ xout)
{
    __shared__ __align__(16) u16 Plds[4][32 * 32];   // [row<32][k<32] per wave
    __shared__ __align__(16) u16 VTlds[4][64 * 32];  // [c<64][k<32]  per wave

    const int tid = threadIdx.x;
    const int wave = tid >> 6, lane = tid & 63;
    const int lr = lane & 15, lg = lane >> 4;
    const size_t rowbase = (size_t)blockIdx.x * NL;
    u16* P  = Plds[wave];
    u16* VT = VTlds[wave];

    for (int hh = 0; hh < 2; ++hh) {
        const int h = wave * 2 + hh;

        // ---- load fragments (rows clamped to 23: avoids OOB + inf in pad rows)
        s16x8 qf[2][2], kf[2][2], vf[2][2];
#pragma unroll
        for (int m = 0; m < 2; ++m) {
            int rq = m * 16 + lr; int r = rq > 23 ? 23 : rq;
            const u16* q_ = qp  + (rowbase + r) * 512  + h * 64 + lg * 8;
            const u16* k_ = kvp + (rowbase + r) * 1024 + h * 64 + lg * 8;
            const u16* v_ = vun + (rowbase + r) * 512  + h * 64 + lg * 8;
#pragma unroll
            for (int ks = 0; ks < 2; ++ks) {
                qf[m][ks] = *(const s16x8*)(q_ + ks * 32);
                kf[m][ks] = *(const s16x8*)(k_ + ks * 32);
                vf[m][ks] = *(const s16x8*)(v_ + ks * 32);
            }
        }

        // ---- row norms via in-register shfl_xor reduce
        float invq[2], invk[2], invv[2];
#pragma unroll
        for (int m = 0; m < 2; ++m) {
            float sq = 0.f, sk = 0.f, sv = 0.f;
#pragma unroll
            for (int ks = 0; ks < 2; ++ks)
#pragma unroll
                for (int j = 0; j < 8; ++j) {
                    float a = bf2f((u16)qf[m][ks][j]); sq += a * a;
                    float b = bf2f((u16)kf[m][ks][j]); sk += b * b;
                    float c = bf2f((u16)vf[m][ks][j]); sv += c * c;
                }
            sq += __shfl_xor(sq, 16); sq += __shfl_xor(sq, 32);
            sk += __shfl_xor(sk, 16); sk += __shfl_xor(sk, 32);
            sv += __shfl_xor(sv, 16); sv += __shfl_xor(sv, 32);
            invq[m] = 1.f / fmaxf(sqrtf(sq), 1e-12f);
            invk[m] = 1.f / fmaxf(sqrtf(sk), 1e-12f);
            invv[m] = 1.f / fmaxf(sqrtf(sv), 1e-12f);
        }

        // ---- S = Q K^T
        f32x4 sc[2][2] = {};
#pragma unroll
        for (int m = 0; m < 2; ++m)
#pragma unroll
            for (int n = 0; n < 2; ++n)
#pragma unroll
                for (int ks = 0; ks < 2; ++ks)
                    sc[m][n] = __builtin_amdgcn_mfma_f32_16x16x32_bf16(
                        qf[m][ks], kf[n][ks], sc[m][n], 0, 0, 0);

        // ---- scale + softmax (row r = m*16 + lg*4 + j, cols = lr / 16+lr)
#pragma unroll
        for (int m = 0; m < 2; ++m) {
#pragma unroll
            for (int j = 0; j < 4; ++j) {
                float nq = __shfl(invq[m], lg * 4 + j);
                float a0 = sc[m][0][j] * nq * invk[0] * 0.125f;
                float a1 = (lr < 8) ? sc[m][1][j] * nq * invk[1] * 0.125f : -3.0e38f;
                float mx = fmaxf(a0, a1);
#pragma unroll
                for (int d = 1; d < 16; d <<= 1) mx = fmaxf(mx, __shfl_xor(mx, d));
                float e0 = __expf(a0 - mx);
                float e1 = (lr < 8) ? __expf(a1 - mx) : 0.f;
                float s = e0 + e1;
#pragma unroll
                for (int d = 1; d < 16; d <<= 1) s += __shfl_xor(s, d);
                float inv = 1.f / s;
                int r = m * 16 + lg * 4 + j;
                P[r * 32 + lr]      = f2bf(e0 * inv);
                P[r * 32 + 16 + lr] = f2bf(e1 * inv);   // cols 24-31 get 0
            }
        }

        // ---- normalized V^T into LDS: V[r][c] -> VT[c*32 + r]
#pragma unroll
        for (int m = 0; m < 2; ++m)
#pragma unroll
            for (int ks = 0; ks < 2; ++ks)
#pragma unroll
                for (int j = 0; j < 8; ++j) {
                    int c = ks * 32 + lg * 8 + j;
                    int r = m * 16 + lr;
                    VT[c * 32 + r] = f2bf(bf2f((u16)vf[m][ks][j]) * invv[m]);
                }

        asm volatile("s_waitcnt lgkmcnt(0)" ::: "memory");
        __builtin_amdgcn_sched_barrier(0);

        // ---- X = P V
        s16x8 pa[2], vb[4];
#pragma unroll
        for (int m = 0; m < 2; ++m)
            pa[m] = *(const s16x8*)&P[(m * 16 + lr) * 32 + lg * 8];
#pragma unroll
        for (int n = 0; n < 4; ++n)
            vb[n] = *(const s16x8*)&VT[(n * 16 + lr) * 32 + lg * 8];

        f32x4 xa[2][4] = {};
#pragma unroll
        for (int m = 0; m < 2; ++m)
#pragma unroll
            for (int n = 0; n < 4; ++n)
                xa[m][n] = __builtin_amdgcn_mfma_f32_16x16x32_bf16(
                    pa[m], vb[n], xa[m][n], 0, 0, 0);

        // ---- store rows < 24
#pragma unroll
        for (int m = 0; m < 2; ++m)
#pragma unroll
            for (int n = 0; n < 4; ++n)
#pragma unroll
                for (int j = 0; j < 4; ++j) {
                    int r = m * 16 + lg * 4 + j;
                    if (r < 24)
                        xout[(rowbase + r) * 512 + h * 64 + n * 16 + lr] =
                            f2bf(xa[m][n][j]);
                }

        // wave-local LDS reuse across heads: in-order DS pipe + compiler waits
        asm volatile("s_waitcnt lgkmcnt(0)" ::: "memory");
        __builtin_amdgcn_sched_barrier(0);
    }
}

// ---------------------------------------------------------------------------
extern "C" void kernel_launch(void* const* d_in, const int* in_sizes, int n_in,
                              void* d_out, int out_size, void* d_ws, size_t ws_size,
                              hipStream_t stream)
{
    const float* q      = (const float*)d_in[0];
    const float* kv     = (const float*)d_in[1];
    const float* Wq     = (const float*)d_in[2];
    const float* bq     = (const float*)d_in[3];
    const float* Wkv    = (const float*)d_in[4];
    const float* bkv    = (const float*)d_in[5];
    const float* Wg     = (const float*)d_in[6];
    const float* bg     = (const float*)d_in[7];
    const float* v_init = (const float*)d_in[8];
    const float* Wm     = (const float*)d_in[9];
    const float* bm     = (const float*)d_in[10];

    char* ws = (char*)d_ws;
    const size_t SZ = (size_t)NR * NC;
    u16* buf0   = (u16*)(ws);                      // qbf -> later x
    u16* buf1   = (u16*)(ws + 2 * SZ);             // kvbf -> later v_unnorm
    u16* qp     = (u16*)(ws + 4 * SZ);
    u16* kvp    = (u16*)(ws + 6 * SZ);             // [R,1024]
    char* wbase = ws + 10 * SZ;
    u16* Wq_t   = (u16*)(wbase);
    u16* Wkv_t  = (u16*)(wbase + 512 * 512 * 2);
    u16* Wg_t   = (u16*)(wbase + 512 * 512 * 2 + 1024 * 512 * 2);
    u16* Wm_t   = (u16*)(wbase + 2 * 512 * 512 * 2 + 1024 * 512 * 2);
    float* tvi  = (float*)(wbase + 3 * 512 * 512 * 2 + 1024 * 512 * 2);

    convert_kernel<<<1024, 256, 0, stream>>>(q, kv, Wq, Wkv, Wg, Wm, v_init,
                                             buf0, buf1, Wq_t, Wkv_t, Wg_t, Wm_t, tvi);

    gemm_kernel<1><<<dim3(NR / 128, 8), 256, 0, stream>>>(buf1, 512, Wkv_t, bkv,
                                                          kvp, 1024, nullptr);
    gemm_kernel<0><<<dim3(NR / 128, 4), 256, 0, stream>>>(buf0, 512, Wq_t, bq,
                                                          qp, 512, nullptr);
    gemm_kernel<2><<<dim3(NR / 128, 4), 256, 0, stream>>>(kvp + 512, 1024, Wg_t, bg,
                                                          buf1, 512, tvi);

    attn_kernel<<<dim3(NBT), 256, 0, stream>>>(qp, kvp, buf1, buf0);

    gemm_kernel<3><<<dim3(NR / 128, 4), 256, 0, stream>>>(buf0, 512, Wm_t, bm,
                                                          d_out, 512, q);
}

// Round 8
// 578.224 us; speedup vs baseline: 1.0393x; 1.0042x over previous
//
#include <hip/hip_runtime.h>
#include <math.h>

typedef unsigned short u16;
typedef __attribute__((ext_vector_type(8))) short s16x8;
typedef __attribute__((ext_vector_type(4))) float f32x4;

#define NB 8
#define NT 256
#define NL 24
#define NC 512
#define NH 8
#define ND 64
#define NR (NB*NT*NL)        // 49152 rows
#define NBT (NB*NT)          // 2048
#define NMB (NR/128)         // 384 row-blocks

__device__ __forceinline__ u16 f2bf(float f) {
    unsigned u = __float_as_uint(f);
    u = (u + 0x7fffu + ((u >> 16) & 1u)) >> 16;
    return (u16)u;
}
__device__ __forceinline__ float bf2f(u16 h) {
    return __uint_as_float(((unsigned)h) << 16);
}

// ---------------------------------------------------------------------------
// Kernel 1: convert inputs to bf16, transpose weights to [N][K] bf16,
//           precompute tanh(v_init).
// ---------------------------------------------------------------------------
__global__ void convert_kernel(const float* __restrict__ q, const float* __restrict__ kv,
                               const float* __restrict__ Wq, const float* __restrict__ Wkv,
                               const float* __restrict__ Wg, const float* __restrict__ Wm,
                               const float* __restrict__ v_init,
                               u16* __restrict__ qbf, u16* __restrict__ kvbf,
                               u16* __restrict__ Wq_t, u16* __restrict__ Wkv_t,
                               u16* __restrict__ Wg_t, u16* __restrict__ Wm_t,
                               float* __restrict__ tvi)
{
    const int stride = gridDim.x * blockDim.x;
    const int t0 = blockIdx.x * blockDim.x + threadIdx.x;

    const long long n4 = (long long)NR * NC / 4;
    for (long long i = t0; i < n4; i += stride) {
        float4 a = ((const float4*)q)[i];
        ushort4 oa;
        oa.x = f2bf(a.x); oa.y = f2bf(a.y); oa.z = f2bf(a.z); oa.w = f2bf(a.w);
        ((ushort4*)qbf)[i] = oa;
        float4 b = ((const float4*)kv)[i];
        ushort4 ob;
        ob.x = f2bf(b.x); ob.y = f2bf(b.y); ob.z = f2bf(b.z); ob.w = f2bf(b.w);
        ((ushort4*)kvbf)[i] = ob;
    }
    for (int e = t0; e < 512 * 512; e += stride) {
        int n = e >> 9, k = e & 511;
        Wq_t[e] = f2bf(Wq[k * 512 + n]);
        Wg_t[e] = f2bf(Wg[k * 512 + n]);
        Wm_t[e] = f2bf(Wm[k * 512 + n]);
    }
    for (int e = t0; e < 1024 * 512; e += stride) {
        int n = e >> 9, k = e & 511;
        Wkv_t[e] = f2bf(Wkv[k * 1024 + n]);
    }
    for (int e = t0; e < NL * NC; e += stride) {
        tvi[e] = tanhf(v_init[e]);
    }
}

// ---------------------------------------------------------------------------
// Epilogue helper shared by both GEMM variants. Lane holds C[row][col0..col0+3].
// ---------------------------------------------------------------------------
template <int MODE>
__device__ __forceinline__ void epilogue_store(
    const f32x4& a, int row, int col0, const float* bias,
    void* out, int ldo, const float* extra)
{
    float4 bv = *(const float4*)&bias[col0];
    float v0 = a[0] + bv.x, v1 = a[1] + bv.y, v2 = a[2] + bv.z, v3 = a[3] + bv.w;
    if constexpr (MODE == 0 || MODE == 1) {
        ushort4 o = { f2bf(v0), f2bf(v1), f2bf(v2), f2bf(v3) };
        *(ushort4*)&((u16*)out)[(size_t)row * ldo + col0] = o;
    } else if constexpr (MODE == 2) {
        float4 tv = *(const float4*)&extra[(row % NL) * NC + col0];
        float g0 = 1.f / (1.f + __expf(-v0));
        float g1 = 1.f / (1.f + __expf(-v1));
        float g2 = 1.f / (1.f + __expf(-v2));
        float g3 = 1.f / (1.f + __expf(-v3));
        ushort4 o = { f2bf(fmaxf(g0 * tv.x, 0.f)), f2bf(fmaxf(g1 * tv.y, 0.f)),
                      f2bf(fmaxf(g2 * tv.z, 0.f)), f2bf(fmaxf(g3 * tv.w, 0.f)) };
        *(ushort4*)&((u16*)out)[(size_t)row * ldo + col0] = o;
    } else {
        float4 sc = *(const float4*)&extra[(size_t)row * NC + col0];
        float4 o = { v0 + sc.x, v1 + sc.y, v2 + sc.z, v3 + sc.w };
        *(float4*)&((float*)out)[(size_t)row * ldo + col0] = o;
    }
}

// ---------------------------------------------------------------------------
// gemm_db: 8-wave (512t) 128x128 tile, BK=32, 2-buf LDS (32 KB), 2-deep
// counted vmcnt, 2 barriers/iter. XCD-bijective swizzled 1-D grid, nb-fastest.
// Per wave: 64x32 output (acc[4][2] = 32 AGPR) -> high occupancy.
// LDS chunk swizzle as R7 (both-sides, rule #21): LDS[row][c] holds global
// chunk c ^ ((row>>1)&3); read chunk = lg ^ ((lrow>>1)&3).
// ---------------------------------------------------------------------------
template <int MODE, int NNB_LOG2>
__global__ __launch_bounds__(512)
void gemm_db(const u16* __restrict__ A, int lda,
             const u16* __restrict__ Bt,
             const float* __restrict__ bias,
             void* __restrict__ out, int ldo,
             const float* __restrict__ extra)
{
    __shared__ __align__(16) u16 Alds[2][128 * 32];
    __shared__ __align__(16) u16 Blds[2][128 * 32];

    const int tid = threadIdx.x;               // 0..511
    // XCD-bijective swizzle: XCD x owns contiguous swz range, nb fastest.
    const int cpx = (NMB << NNB_LOG2) >> 3;
    const int wgl = blockIdx.x;
    const int swz = (wgl & 7) * cpx + (wgl >> 3);
    const int nb = swz & ((1 << NNB_LOG2) - 1);
    const int mb = swz >> NNB_LOG2;

    const int wave = tid >> 6, lane = tid & 63;
    const int wr = wave >> 2, wc = wave & 3;   // 2 row-groups x 4 col-groups
    const int lrow = lane & 15, lg = lane >> 4;
    const int rko = (lg ^ ((lrow >> 1) & 3)) * 8;   // swizzled read chunk

    f32x4 acc[4][2] = {};

    // staging: 512 chunks of 16B; thread -> row=tid>>2, dst chunk=tid&3,
    // swizzled global source chunk = (tid&3) ^ ((row>>1)&3) = (tid&3)^((tid>>3)&3)
    const int srow = tid >> 2;
    const int k8s = (((tid & 3) ^ ((tid >> 3) & 3)) * 8);

#define STAGE(buf, k0)                                                          \
    do {                                                                        \
        const u16* srcA = A + (size_t)(mb * 128 + srow) * lda + (k0) + k8s;     \
        u16* dstA = &Alds[buf][wave * 64 * 8];   /* wave-uniform base */        \
        __builtin_amdgcn_global_load_lds(                                       \
            (const __attribute__((address_space(1))) void*)srcA,                \
            (__attribute__((address_space(3))) void*)dstA, 16, 0, 0);           \
        const u16* srcB = Bt + (size_t)(nb * 128 + srow) * 512 + (k0) + k8s;    \
        u16* dstB = &Blds[buf][wave * 64 * 8];                                  \
        __builtin_amdgcn_global_load_lds(                                       \
            (const __attribute__((address_space(1))) void*)srcB,                \
            (__attribute__((address_space(3))) void*)dstB, 16, 0, 0);           \
    } while (0)

    STAGE(0, 0);
    STAGE(1, 32);

#pragma unroll
    for (int t = 0; t < 16; ++t) {
        // tile t's 2 loads (oldest) done; tile t+1's may stay in flight
        if (t < 15) asm volatile("s_waitcnt vmcnt(2)" ::: "memory");
        else        asm volatile("s_waitcnt vmcnt(0)" ::: "memory");
        __builtin_amdgcn_s_barrier();

        const int cb = t & 1;
        s16x8 bfr[2];
#pragma unroll
        for (int n = 0; n < 2; ++n)
            bfr[n] = *(const s16x8*)&Blds[cb][(wc * 32 + n * 16 + lrow) * 32 + rko];
#pragma unroll
        for (int m = 0; m < 4; ++m) {
            s16x8 af = *(const s16x8*)&Alds[cb][(wr * 64 + m * 16 + lrow) * 32 + rko];
#pragma unroll
            for (int n = 0; n < 2; ++n)
                acc[m][n] = __builtin_amdgcn_mfma_f32_16x16x32_bf16(
                    bfr[n], af, acc[m][n], 0, 0, 0);
        }

        // all ds_reads of buf[cb] complete block-wide before overwrite
        asm volatile("s_waitcnt lgkmcnt(0)" ::: "memory");
        __builtin_amdgcn_s_barrier();
        if (t < 14) STAGE(t & 1, (t + 2) * 32);
    }
#undef STAGE

    const int rbase = mb * 128 + wr * 64;
    const int cbase = nb * 128 + wc * 32;
#pragma unroll
    for (int m = 0; m < 4; ++m) {
        const int row = rbase + m * 16 + lrow;
#pragma unroll
        for (int n = 0; n < 2; ++n)
            epilogue_store<MODE>(acc[m][n], row, cbase + n * 16 + lg * 4,
                                 bias, out, ldo, extra);
    }
}

// ---------------------------------------------------------------------------
// gemm_tb: R7 control structure (4-wave, 3-buf, counted vmcnt, 1 barrier/iter)
// + XCD-bijective swizzled 1-D grid. Used for MODE 3 only (control arm).
// ---------------------------------------------------------------------------
template <int MODE, int NNB_LOG2>
__global__ __launch_bounds__(256)
void gemm_tb(const u16* __restrict__ A, int lda,
             const u16* __restrict__ Bt,
             const float* __restrict__ bias,
             void* __restrict__ out, int ldo,
             const float* __restrict__ extra)
{
    __shared__ __align__(16) u16 Alds[3][128 * 32];
    __shared__ __align__(16) u16 Blds[3][128 * 32];

    const int tid = threadIdx.x;
    const int cpx = (NMB << NNB_LOG2) >> 3;
    const int wgl = blockIdx.x;
    const int swz = (wgl & 7) * cpx + (wgl >> 3);
    const int nb = swz & ((1 << NNB_LOG2) - 1);
    const int mb = swz >> NNB_LOG2;

    const int wave = tid >> 6, lane = tid & 63;
    const int wr = wave >> 1, wc = wave & 1;
    const int lrow = lane & 15;
    const int lg = lane >> 4;
    const int rko = (lg ^ ((lrow >> 1) & 3)) * 8;

    f32x4 acc[4][4] = {};

    const int row_a[2] = { tid >> 2, (256 + tid) >> 2 };
    const int k8s = (((tid & 3) ^ ((tid >> 3) & 3)) * 8);

#define STAGE(buf, k0)                                                          \
    do {                                                                        \
        _Pragma("unroll")                                                       \
        for (int c = 0; c < 2; ++c) {                                           \
            const u16* srcA = A + (size_t)(mb * 128 + row_a[c]) * lda + (k0) + k8s; \
            u16* dstA = &Alds[buf][(c * 256 + wave * 64) * 8];                  \
            __builtin_amdgcn_global_load_lds(                                   \
                (const __attribute__((address_space(1))) void*)srcA,            \
                (__attribute__((address_space(3))) void*)dstA, 16, 0, 0);       \
        }                                                                       \
        _Pragma("unroll")                                                       \
        for (int c = 0; c < 2; ++c) {                                           \
            const u16* srcB = Bt + (size_t)(nb * 128 + row_a[c]) * 512 + (k0) + k8s; \
            u16* dstB = &Blds[buf][(c * 256 + wave * 64) * 8];                  \
            __builtin_amdgcn_global_load_lds(                                   \
                (const __attribute__((address_space(1))) void*)srcB,            \
                (__attribute__((address_space(3))) void*)dstB, 16, 0, 0);       \
        }                                                                       \
    } while (0)

    STAGE(0, 0);
    STAGE(1, 32);

#pragma unroll
    for (int t = 0; t < 16; ++t) {
        if (t < 15) asm volatile("s_waitcnt vmcnt(4)" ::: "memory");
        else        asm volatile("s_waitcnt vmcnt(0)" ::: "memory");
        __builtin_amdgcn_s_barrier();

        const int cb = t % 3;
        s16x8 af[4], bfr[4];
#pragma unroll
        for (int m = 0; m < 4; ++m)
            af[m] = *(const s16x8*)&Alds[cb][(wr * 64 + m * 16 + lrow) * 32 + rko];
#pragma unroll
        for (int n = 0; n < 4; ++n)
            bfr[n] = *(const s16x8*)&Blds[cb][(wc * 64 + n * 16 + lrow) * 32 + rko];
#pragma unroll
        for (int m = 0; m < 4; ++m)
#pragma unroll
            for (int n = 0; n < 4; ++n)
                acc[m][n] = __builtin_amdgcn_mfma_f32_16x16x32_bf16(
                    bfr[n], af[m], acc[m][n], 0, 0, 0);

        if (t < 14) STAGE((t + 2) % 3, (t + 2) * 32);
    }
#undef STAGE

    const int rbase = mb * 128 + wr * 64;
    const int cbase = nb * 128 + wc * 64;
#pragma unroll
    for (int m = 0; m < 4; ++m) {
        const int row = rbase + m * 16 + lrow;
#pragma unroll
        for (int n = 0; n < 4; ++n)
            epilogue_store<MODE>(acc[m][n], row, cbase + n * 16 + lg * 4,
                                 bias, out, ldo, extra);
    }
}

// ---------------------------------------------------------------------------
// MFMA attention: block = 4 waves, one (b,t) per block, each wave does 2 heads.
// ---------------------------------------------------------------------------
__global__ __launch_bounds__(256)
void attn_kernel(const u16* __restrict__ qp, const u16* __restrict__ kvp,
                 const u16* __restrict__ vun, u16* __restrict__ xout)
{
    __shared__ __align__(16) u16 Plds[4][32 * 32];   // [row<32][k<32] per wave
    __shared__ __align__(16) u16 VTlds[4][64 * 32];  // [c<64][k<32]  per wave

    const int tid = threadIdx.x;
    const int wave = tid >> 6, lane = tid & 63;
    const int lr = lane & 15, lg = lane >> 4;
    const size_t rowbase = (size_t)blockIdx.x * NL;
    u16* P  = Plds[wave];
    u16* VT = VTlds[wave];

    for (int hh = 0; hh < 2; ++hh) {
        const int h = wave * 2 + hh;

        // ---- load fragments (rows clamped to 23: avoids OOB + inf in pad rows)
        s16x8 qf[2][2], kf[2][2], vf[2][2];
#pragma unroll
        for (int m = 0; m < 2; ++m) {
            int rq = m * 16 + lr; int r = rq > 23 ? 23 : rq;
            const u16* q_ = qp  + (rowbase + r) * 512  + h * 64 + lg * 8;
            const u16* k_ = kvp + (rowbase + r) * 1024 + h * 64 + lg * 8;
            const u16* v_ = vun + (rowbase + r) * 512  + h * 64 + lg * 8;
#pragma unroll
            for (int ks = 0; ks < 2; ++ks) {
                qf[m][ks] = *(const s16x8*)(q_ + ks * 32);
                kf[m][ks] = *(const s16x8*)(k_ + ks * 32);
                vf[m][ks] = *(const s16x8*)(v_ + ks * 32);
            }
        }

        // ---- row norms via in-register shfl_xor reduce
        float invq[2], invk[2], invv[2];
#pragma unroll
        for (int m = 0; m < 2; ++m) {
            float sq = 0.f, sk = 0.f, sv = 0.f;
#pragma unroll
            for (int ks = 0; ks < 2; ++ks)
#pragma unroll
                for (int j = 0; j < 8; ++j) {
                    float a = bf2f((u16)qf[m][ks][j]); sq += a * a;
                    float b = bf2f((u16)kf[m][ks][j]); sk += b * b;
                    float c = bf2f((u16)vf[m][ks][j]); sv += c * c;
                }
            sq += __shfl_xor(sq, 16); sq += __shfl_xor(sq, 32);
            sk += __shfl_xor(sk, 16); sk += __shfl_xor(sk, 32);
            sv += __shfl_xor(sv, 16); sv += __shfl_xor(sv, 32);
            invq[m] = 1.f / fmaxf(sqrtf(sq), 1e-12f);
            invk[m] = 1.f / fmaxf(sqrtf(sk), 1e-12f);
            invv[m] = 1.f / fmaxf(sqrtf(sv), 1e-12f);
        }

        // ---- S = Q K^T
        f32x4 sc[2][2] = {};
#pragma unroll
        for (int m = 0; m < 2; ++m)
#pragma unroll
            for (int n = 0; n < 2; ++n)
#pragma unroll
                for (int ks = 0; ks < 2; ++ks)
                    sc[m][n] = __builtin_amdgcn_mfma_f32_16x16x32_bf16(
                        qf[m][ks], kf[n][ks], sc[m][n], 0, 0, 0);

        // ---- scale + softmax (row r = m*16 + lg*4 + j, cols = lr / 16+lr)
#pragma unroll
        for (int m = 0; m < 2; ++m) {
#pragma unroll
            for (int j = 0; j < 4; ++j) {
                float nq = __shfl(invq[m], lg * 4 + j);
                float a0 = sc[m][0][j] * nq * invk[0] * 0.125f;
                float a1 = (lr < 8) ? sc[m][1][j] * nq * invk[1] * 0.125f : -3.0e38f;
                float mx = fmaxf(a0, a1);
#pragma unroll
                for (int d = 1; d < 16; d <<= 1) mx = fmaxf(mx, __shfl_xor(mx, d));
                float e0 = __expf(a0 - mx);
                float e1 = (lr < 8) ? __expf(a1 - mx) : 0.f;
                float s = e0 + e1;
#pragma unroll
                for (int d = 1; d < 16; d <<= 1) s += __shfl_xor(s, d);
                float inv = 1.f / s;
                int r = m * 16 + lg * 4 + j;
                P[r * 32 + lr]      = f2bf(e0 * inv);
                P[r * 32 + 16 + lr] = f2bf(e1 * inv);   // cols 24-31 get 0
            }
        }

        // ---- normalized V^T into LDS: V[r][c] -> VT[c*32 + r]
#pragma unroll
        for (int m = 0; m < 2; ++m)
#pragma unroll
            for (int ks = 0; ks < 2; ++ks)
#pragma unroll
                for (int j = 0; j < 8; ++j) {
                    int c = ks * 32 + lg * 8 + j;
                    int r = m * 16 + lr;
                    VT[c * 32 + r] = f2bf(bf2f((u16)vf[m][ks][j]) * invv[m]);
                }

        asm volatile("s_waitcnt lgkmcnt(0)" ::: "memory");
        __builtin_amdgcn_sched_barrier(0);

        // ---- X = P V
        s16x8 pa[2], vb[4];
#pragma unroll
        for (int m = 0; m < 2; ++m)
            pa[m] = *(const s16x8*)&P[(m * 16 + lr) * 32 + lg * 8];
#pragma unroll
        for (int n = 0; n < 4; ++n)
            vb[n] = *(const s16x8*)&VT[(n * 16 + lr) * 32 + lg * 8];

        f32x4 xa[2][4] = {};
#pragma unroll
        for (int m = 0; m < 2; ++m)
#pragma unroll
            for (int n = 0; n < 4; ++n)
                xa[m][n] = __builtin_amdgcn_mfma_f32_16x16x32_bf16(
                    pa[m], vb[n], xa[m][n], 0, 0, 0);

        // ---- store rows < 24
#pragma unroll
        for (int m = 0; m < 2; ++m)
#pragma unroll
            for (int n = 0; n < 4; ++n)
#pragma unroll
                for (int j = 0; j < 4; ++j) {
                    int r = m * 16 + lg * 4 + j;
                    if (r < 24)
                        xout[(rowbase + r) * 512 + h * 64 + n * 16 + lr] =
                            f2bf(xa[m][n][j]);
                }

        // wave-local LDS reuse across heads: in-order DS pipe + compiler waits
        asm volatile("s_waitcnt lgkmcnt(0)" ::: "memory");
        __builtin_amdgcn_sched_barrier(0);
    }
}

// ---------------------------------------------------------------------------
extern "C" void kernel_launch(void* const* d_in, const int* in_sizes, int n_in,
                              void* d_out, int out_size, void* d_ws, size_t ws_size,
                              hipStream_t stream)
{
    const float* q      = (const float*)d_in[0];
    const float* kv     = (const float*)d_in[1];
    const float* Wq     = (const float*)d_in[2];
    const float* bq     = (const float*)d_in[3];
    const float* Wkv    = (const float*)d_in[4];
    const float* bkv    = (const float*)d_in[5];
    const float* Wg     = (const float*)d_in[6];
    const float* bg     = (const float*)d_in[7];
    const float* v_init = (const float*)d_in[8];
    const float* Wm     = (const float*)d_in[9];
    const float* bm     = (const float*)d_in[10];

    char* ws = (char*)d_ws;
    const size_t SZ = (size_t)NR * NC;
    u16* buf0   = (u16*)(ws);                      // qbf -> later x
    u16* buf1   = (u16*)(ws + 2 * SZ);             // kvbf -> later v_unnorm
    u16* qp     = (u16*)(ws + 4 * SZ);
    u16* kvp    = (u16*)(ws + 6 * SZ);             // [R,1024]
    char* wbase = ws + 10 * SZ;
    u16* Wq_t   = (u16*)(wbase);
    u16* Wkv_t  = (u16*)(wbase + 512 * 512 * 2);
    u16* Wg_t   = (u16*)(wbase + 512 * 512 * 2 + 1024 * 512 * 2);
    u16* Wm_t   = (u16*)(wbase + 2 * 512 * 512 * 2 + 1024 * 512 * 2);
    float* tvi  = (float*)(wbase + 3 * 512 * 512 * 2 + 1024 * 512 * 2);

    convert_kernel<<<1024, 256, 0, stream>>>(q, kv, Wq, Wkv, Wg, Wm, v_init,
                                             buf0, buf1, Wq_t, Wkv_t, Wg_t, Wm_t, tvi);

    // kvp = kv @ Wkv + bkv   [R,1024] bf16   (8-wave db, N/128=8 -> log2 3)
    gemm_db<1, 3><<<NMB * 8, 512, 0, stream>>>(buf1, 512, Wkv_t, bkv,
                                               kvp, 1024, nullptr);
    // qp = q @ Wq + bq       [R,512] bf16
    gemm_db<0, 2><<<NMB * 4, 512, 0, stream>>>(buf0, 512, Wq_t, bq,
                                               qp, 512, nullptr);
    // v_un = relu(sigmoid(v_lin @ Wg + bg) * tanh(v_init)) -> buf1
    gemm_db<2, 2><<<NMB * 4, 512, 0, stream>>>(kvp + 512, 1024, Wg_t, bg,
                                               buf1, 512, tvi);

    attn_kernel<<<dim3(NBT), 256, 0, stream>>>(qp, kvp, buf1, buf0);

    // out = x @ Wm + bm + q  (f32)  -- control arm: R7 3-buf structure + swizzle
    gemm_tb<3, 2><<<NMB * 4, 256, 0, stream>>>(buf0, 512, Wm_t, bm,
                                               d_out, 512, q);
}